// Round 10
// baseline (137.626 us; speedup 1.0000x reference)
//
#include <hip/hip_runtime.h>

#define BLOCK      256
#define DC         16               // distinct db chunks
#define DCX        32               // chunk slots incl. 2x idempotent dup (DIAGNOSTIC:
                                    // forces pass > fill band if still slow -> counters)
#define CHUNKPTS   1024             // db points per chunk
#define CHUNKBYTES (CHUNKPTS * 32)  // 32 KB packed
#define NQ         16384

typedef _Float16 f16;
typedef __attribute__((ext_vector_type(8)))  _Float16 f16x8;
typedef __attribute__((ext_vector_type(16))) float    f32x16;

union Pack { f16 h[16]; uint4 u[2]; };
union U8   { uint4 u; f16x8 v; };

__device__ __forceinline__ void split(float v, f16& h, f16& l) {
    h = (f16)v;
    l = (f16)(v - (float)h);
}

// db-side K-row: B[k] = {ph(3), pl(3), ph(3), pl(3), n2h, n2l, 0, 0}
__device__ __forceinline__ Pack pack_db(float x, float y, float z) {
    f16 hx, lx, hy, ly, hz, lz, nh, nl;
    split(x, hx, lx); split(y, hy, ly); split(z, hz, lz);
    float n2 = fmaf(x, x, fmaf(y, y, z * z));
    split(n2, nh, nl);
    Pack p;
    p.h[0] = hx;  p.h[1] = hy;  p.h[2] = hz;
    p.h[3] = lx;  p.h[4] = ly;  p.h[5] = lz;
    p.h[6] = hx;  p.h[7] = hy;  p.h[8] = hz;
    p.h[9] = lx;  p.h[10] = ly; p.h[11] = lz;
    p.h[12] = nh; p.h[13] = nl; p.h[14] = (f16)0.f; p.h[15] = (f16)0.f;
    return p;
}

// query-side K-row: A[k] = {-2qh(3), -2qh(3), -2ql(3), -2ql(3), 1, 1, 0, 0}
// pairing with B gives  -2*(qh+ql).(ph+pl) + |p|^2  to ~2^-22 relative.
__device__ __forceinline__ Pack pack_q(float x, float y, float z) {
    f16 hx, lx, hy, ly, hz, lz;
    split(-2.f * x, hx, lx); split(-2.f * y, hy, ly); split(-2.f * z, hz, lz);
    Pack p;
    p.h[0] = hx; p.h[1] = hy; p.h[2] = hz;
    p.h[3] = hx; p.h[4] = hy; p.h[5] = hz;
    p.h[6] = lx; p.h[7] = ly; p.h[8] = lz;
    p.h[9] = lx; p.h[10] = ly; p.h[11] = lz;
    p.h[12] = (f16)1.f; p.h[13] = (f16)1.f; p.h[14] = (f16)0.f; p.h[15] = (f16)0.f;
    return p;
}

// sigma-swizzle on the 16B-granule index within each 64-granule (1 KB) group.
// Bijective involution; verified r6/r8 (absmax 0.0; conflicts 3.6M -> 1.05M cyc).
__device__ __forceinline__ int sigma(int g) { return g ^ ((g >> 3) & 1); }

// Pack A/B fragment arrays ONCE. B granules stored sigma-permuted per group.
__global__ __launch_bounds__(BLOCK) void chamfer_prep(
    const float* __restrict__ Xc, const float* __restrict__ Xt,
    uint4* __restrict__ Ac, uint4* __restrict__ At,
    uint4* __restrict__ Bc, uint4* __restrict__ Bt,
    float* __restrict__ out)
{
    int i = blockIdx.x * BLOCK + threadIdx.x;
    if (i == 0) out[0] = 0.0f;   // stream-ordered before reduce's atomicAdd
    const int grp = i >> 5, c = i & 31;
    const int s0 = grp * 64 + sigma(2 * c);
    const int s1 = grp * 64 + sigma(2 * c + 1);

    float x = Xc[3 * i], y = Xc[3 * i + 1], z = Xc[3 * i + 2];
    Pack a = pack_q(x, y, z), b = pack_db(x, y, z);
    Ac[2 * i] = a.u[0]; Ac[2 * i + 1] = a.u[1];
    Bc[s0] = b.u[0];    Bc[s1] = b.u[1];

    x = Xt[3 * i]; y = Xt[3 * i + 1]; z = Xt[3 * i + 2];
    a = pack_q(x, y, z); b = pack_db(x, y, z);
    At[2 * i] = a.u[0]; At[2 * i + 1] = a.u[1];
    Bt[s0] = b.u[0];    Bt[s1] = b.u[1];
}

// LATENCY THEORY (r1/r5/r8 all ~40us, MFMA-busy invariant 6.6us, issue floor
// ~5us): unroll-1 body was a serial chain stalling on ds_read latency and MFMA
// writeback (~70cy) twice per iteration. This version software-pipelines 1-deep:
// fold of iteration it-1's MFMA results happens between the ds_read issue and
// the MFMA issue of iteration it -- both latencies hidden. #pragma unroll 1
// retained for spill control (r3/r6 lesson: 252 VGPR when unrolled).
__global__ __launch_bounds__(BLOCK) void chamfer_pass(
    const uint4* __restrict__ Ac, const uint4* __restrict__ At,
    const uint4* __restrict__ Bc, const uint4* __restrict__ Bt,
    float* __restrict__ part)
{
    __shared__ uint4 tile[CHUNKPTS * 2];   // 32 KB

    const int tid  = threadIdx.x;
    const int lane = tid & 63;
    const int w    = tid >> 6;
    const int col  = lane & 31;   // A row / B col within a 32x32 tile
    const int ksel = lane >> 5;   // K-half selector
    const int chunk = blockIdx.y & (DC - 1);   // duplicate slots y and y+16
                                               // process the same chunk (idempotent min)

    const uint4* Aq = blockIdx.z ? At : Ac;
    const char*  Bd = (const char*)(blockIdx.z ? Bc : Bt);

    // ---- stage the whole 32 KB chunk: 8 x global_load_lds(16B)/thread ----
    {
        const char* src = Bd + (size_t)chunk * CHUNKBYTES + tid * 16;
        char*       dst = (char*)tile + tid * 16;
#pragma unroll
        for (int i = 0; i < 8; ++i)
            __builtin_amdgcn_global_load_lds(
                (const __attribute__((address_space(1))) void*)(src + i * 4096),
                (__attribute__((address_space(3))) void*)(dst + i * 4096),
                16, 0, 0);
    }

    // ---- 2 A-tiles (64 queries) per wave while loads fly ----
    const int qw = blockIdx.x * BLOCK + w * 64;
    f16x8 a0, a1;
    {
        U8 u;
        u.u = Aq[(qw + col) * 2 + ksel];      a0 = u.v;
        u.u = Aq[(qw + 32 + col) * 2 + ksel]; a1 = u.v;
    }

    f32x16 acc0, acc1, zacc;
#pragma unroll
    for (int r = 0; r < 16; ++r) { acc0[r] = 3.0e38f; acc1[r] = 3.0e38f; zacc[r] = 0.f; }

    asm volatile("s_waitcnt vmcnt(0)" ::: "memory");
    __syncthreads();   // whole chunk resident; only barrier in the kernel

    // per-lane read slot (sigma-permuted at prep time): loop-invariant
    const char* rb = (const char*)tile + sigma(col * 2 + ksel) * 16;

    // ---- software-pipelined main loop: 16 iters x 2048 B = 32 KB exactly ----
    U8 u0, u1;
    u0.u = *(const uint4*)(rb);
    u1.u = *(const uint4*)(rb + 1024);
    rb += 2048;
    f32x16 d0 = __builtin_amdgcn_mfma_f32_32x32x16_f16(a0, u0.v, zacc, 0, 0, 0);
    f32x16 d1 = __builtin_amdgcn_mfma_f32_32x32x16_f16(a0, u1.v, zacc, 0, 0, 0);
    f32x16 e0 = __builtin_amdgcn_mfma_f32_32x32x16_f16(a1, u0.v, zacc, 0, 0, 0);
    f32x16 e1 = __builtin_amdgcn_mfma_f32_32x32x16_f16(a1, u1.v, zacc, 0, 0, 0);

#pragma unroll 1
    for (int it = 1; it < 16; ++it) {
        U8 v0, v1;                           // issue next B loads (no wait yet)
        v0.u = *(const uint4*)(rb);
        v1.u = *(const uint4*)(rb + 1024);
        rb += 2048;
        // fold PREVIOUS iteration's MFMA results (covers ds_read + mfma latency)
#pragma unroll
        for (int r = 0; r < 16; ++r)   // v_min3_f32
            acc0[r] = fminf(fminf(d0[r], d1[r]), acc0[r]);
#pragma unroll
        for (int r = 0; r < 16; ++r)
            acc1[r] = fminf(fminf(e0[r], e1[r]), acc1[r]);
        // issue all 4 MFMAs back-to-back; results consumed next iteration
        d0 = __builtin_amdgcn_mfma_f32_32x32x16_f16(a0, v0.v, zacc, 0, 0, 0);
        d1 = __builtin_amdgcn_mfma_f32_32x32x16_f16(a0, v1.v, zacc, 0, 0, 0);
        e0 = __builtin_amdgcn_mfma_f32_32x32x16_f16(a1, v0.v, zacc, 0, 0, 0);
        e1 = __builtin_amdgcn_mfma_f32_32x32x16_f16(a1, v1.v, zacc, 0, 0, 0);
    }
#pragma unroll
    for (int r = 0; r < 16; ++r)
        acc0[r] = fminf(fminf(d0[r], d1[r]), acc0[r]);
#pragma unroll
    for (int r = 0; r < 16; ++r)
        acc1[r] = fminf(fminf(e0[r], e1[r]), acc1[r]);

    // ---- min over the 32 db-columns; store per-slot partials ----
#pragma unroll
    for (int r = 0; r < 16; ++r) {
        float v0 = acc0[r], v1 = acc1[r];
#pragma unroll
        for (int off = 1; off < 32; off <<= 1) {
            v0 = fminf(v0, __shfl_xor(v0, off, 64));
            v1 = fminf(v1, __shfl_xor(v1, off, 64));
        }
        if (col == 0) {
            // C/D layout (HW-verified): col=lane&31, row=(r&3)+8*(r>>2)+4*ksel
            int row = (r & 3) + 8 * (r >> 2) + 4 * ksel;
            int q0  = qw + row;
            part[((size_t)blockIdx.z * NQ + q0) * DCX + blockIdx.y]      = v0;
            part[((size_t)blockIdx.z * NQ + q0 + 32) * DCX + blockIdx.y] = v1;
        }
    }
}

// 32-way min over slots, add |q|^2 (recomputed from raw input), clamp, average.
__global__ __launch_bounds__(BLOCK) void chamfer_reduce(
    const float* __restrict__ part, const float* __restrict__ Xc,
    const float* __restrict__ Xt, float* __restrict__ out)
{
    __shared__ float red[4];
    int e = blockIdx.x * BLOCK + threadIdx.x;   // 0 .. 2*NQ-1

    const float4* pb = (const float4*)(part + (size_t)e * DCX);
    float mn = 3.4e38f;
#pragma unroll
    for (int j = 0; j < DCX / 4; ++j) {
        float4 m = pb[j];
        mn = fminf(mn, fminf(fminf(m.x, m.y), fminf(m.z, m.w)));
    }

    const float* X = (e < NQ) ? Xc : Xt;
    int q = (e < NQ) ? e : e - NQ;
    float x = X[3 * q], y = X[3 * q + 1], z = X[3 * q + 2];
    float n2 = fmaf(x, x, fmaf(y, y, z * z));
    float s = fmaxf(mn + n2, 0.0f) * (1.0f / 16384.0f);

#pragma unroll
    for (int off = 32; off > 0; off >>= 1) s += __shfl_down(s, off, 64);
    int wv = threadIdx.x >> 6, ln = threadIdx.x & 63;
    if (ln == 0) red[wv] = s;
    __syncthreads();
    if (threadIdx.x == 0) atomicAdd(out, red[0] + red[1] + red[2] + red[3]);
}

extern "C" void kernel_launch(void* const* d_in, const int* in_sizes, int n_in,
                              void* d_out, int out_size, void* d_ws, size_t ws_size,
                              hipStream_t stream) {
    const float* Xc = (const float*)d_in[0];
    const float* Xt = (const float*)d_in[1];
    float* out = (float*)d_out;

    // ws: Ac | At | Bc | Bt (512 KB each) | part (2*16384*32 f32 = 4 MB)
    uint4* Ac = (uint4*)d_ws;
    uint4* At = Ac + 2 * NQ;
    uint4* Bc = At + 2 * NQ;
    uint4* Bt = Bc + 2 * NQ;
    float* part = (float*)(Bt + 2 * NQ);

    chamfer_prep<<<NQ / BLOCK, BLOCK, 0, stream>>>(Xc, Xt, Ac, At, Bc, Bt, out);

    dim3 grid(NQ / BLOCK /*64*/, DCX, 2);   // 4096 blocks (2x idempotent dup)
    chamfer_pass<<<grid, BLOCK, 0, stream>>>(Ac, At, Bc, Bt, part);

    chamfer_reduce<<<(2 * NQ) / BLOCK, BLOCK, 0, stream>>>(part, Xc, Xt, out);
}

// Round 11
// 90.197 us; speedup vs baseline: 1.5258x; 1.5258x over previous
//
#include <hip/hip_runtime.h>

#define BLOCK      256
#define DC         16               // db chunks (grid.y)
#define CHUNKPTS   1024             // db points per chunk
#define CHUNKBYTES (CHUNKPTS * 32)  // 32 KB packed
#define NQ         16384

typedef _Float16 f16;
typedef __attribute__((ext_vector_type(8)))  _Float16 f16x8;
typedef __attribute__((ext_vector_type(16))) float    f32x16;

union Pack { f16 h[16]; uint4 u[2]; };
union U8   { uint4 u; f16x8 v; };

__device__ __forceinline__ void split(float v, f16& h, f16& l) {
    h = (f16)v;
    l = (f16)(v - (float)h);
}

// db-side K-row: B[k] = {ph(3), pl(3), ph(3), pl(3), n2h, n2l, 0, 0}
__device__ __forceinline__ Pack pack_db(float x, float y, float z) {
    f16 hx, lx, hy, ly, hz, lz, nh, nl;
    split(x, hx, lx); split(y, hy, ly); split(z, hz, lz);
    float n2 = fmaf(x, x, fmaf(y, y, z * z));
    split(n2, nh, nl);
    Pack p;
    p.h[0] = hx;  p.h[1] = hy;  p.h[2] = hz;
    p.h[3] = lx;  p.h[4] = ly;  p.h[5] = lz;
    p.h[6] = hx;  p.h[7] = hy;  p.h[8] = hz;
    p.h[9] = lx;  p.h[10] = ly; p.h[11] = lz;
    p.h[12] = nh; p.h[13] = nl; p.h[14] = (f16)0.f; p.h[15] = (f16)0.f;
    return p;
}

// query-side K-row: A[k] = {-2qh(3), -2qh(3), -2ql(3), -2ql(3), 1, 1, 0, 0}
// pairing with B gives  -2*(qh+ql).(ph+pl) + |p|^2  to ~2^-22 relative.
__device__ __forceinline__ Pack pack_q(float x, float y, float z) {
    f16 hx, lx, hy, ly, hz, lz;
    split(-2.f * x, hx, lx); split(-2.f * y, hy, ly); split(-2.f * z, hz, lz);
    Pack p;
    p.h[0] = hx; p.h[1] = hy; p.h[2] = hz;
    p.h[3] = hx; p.h[4] = hy; p.h[5] = hz;
    p.h[6] = lx; p.h[7] = ly; p.h[8] = lz;
    p.h[9] = lx; p.h[10] = ly; p.h[11] = lz;
    p.h[12] = (f16)1.f; p.h[13] = (f16)1.f; p.h[14] = (f16)0.f; p.h[15] = (f16)0.f;
    return p;
}

// sigma-swizzle on the 16B-granule index within each 64-granule (1 KB) group.
// Bijective involution; verified r6/r8/r10 (absmax 0.0; conflicts 3.6M->1.05M).
__device__ __forceinline__ int sigma(int g) { return g ^ ((g >> 3) & 1); }

// Pack A/B fragment arrays ONCE. B granules stored sigma-permuted per group.
__global__ __launch_bounds__(BLOCK) void chamfer_prep(
    const float* __restrict__ Xc, const float* __restrict__ Xt,
    uint4* __restrict__ Ac, uint4* __restrict__ At,
    uint4* __restrict__ Bc, uint4* __restrict__ Bt,
    float* __restrict__ out)
{
    int i = blockIdx.x * BLOCK + threadIdx.x;
    if (i == 0) out[0] = 0.0f;   // stream-ordered before reduce's atomicAdd
    const int grp = i >> 5, c = i & 31;
    const int s0 = grp * 64 + sigma(2 * c);
    const int s1 = grp * 64 + sigma(2 * c + 1);

    float x = Xc[3 * i], y = Xc[3 * i + 1], z = Xc[3 * i + 2];
    Pack a = pack_q(x, y, z), b = pack_db(x, y, z);
    Ac[2 * i] = a.u[0]; Ac[2 * i + 1] = a.u[1];
    Bc[s0] = b.u[0];    Bc[s1] = b.u[1];

    x = Xt[3 * i]; y = Xt[3 * i + 1]; z = Xt[3 * i + 2];
    a = pack_q(x, y, z); b = pack_db(x, y, z);
    At[2 * i] = a.u[0]; At[2 * i + 1] = a.u[1];
    Bt[s0] = b.u[0];    Bt[s1] = b.u[1];
}

// OCCUPANCY THEORY (r10 counters): 2-A-tile body = ~92 VGPR + ~96 AGPR
// (d0..e1 + accs split to AGPRs, unreported) => ~188 regs => 2 waves/SIMD
// (Occupancy 19.7%) => every pipe <15% busy, all stall. This version: ONE
// A-tile per wave => ~86 total regs; __launch_bounds__(256,4) caps at 128
// => 4-5 waves/SIMD. Work conserved: grid.x 64->128.
__global__ __launch_bounds__(BLOCK, 4) void chamfer_pass(
    const uint4* __restrict__ Ac, const uint4* __restrict__ At,
    const uint4* __restrict__ Bc, const uint4* __restrict__ Bt,
    float* __restrict__ part)
{
    __shared__ uint4 tile[CHUNKPTS * 2];   // 32 KB

    const int tid  = threadIdx.x;
    const int lane = tid & 63;
    const int w    = tid >> 6;
    const int col  = lane & 31;   // A row / B col within a 32x32 tile
    const int ksel = lane >> 5;   // K-half selector

    const uint4* Aq = blockIdx.z ? At : Ac;
    const char*  Bd = (const char*)(blockIdx.z ? Bc : Bt);

    // ---- stage the whole 32 KB chunk: 8 x global_load_lds(16B)/thread ----
    {
        const char* src = Bd + (size_t)blockIdx.y * CHUNKBYTES + tid * 16;
        char*       dst = (char*)tile + tid * 16;
#pragma unroll
        for (int i = 0; i < 8; ++i)
            __builtin_amdgcn_global_load_lds(
                (const __attribute__((address_space(1))) void*)(src + i * 4096),
                (__attribute__((address_space(3))) void*)(dst + i * 4096),
                16, 0, 0);
    }

    // ---- ONE A-tile (32 queries) per wave while loads fly ----
    const int qw = blockIdx.x * (4 * 32) + w * 32;
    f16x8 a0;
    {
        U8 u;
        u.u = Aq[(qw + col) * 2 + ksel];
        a0 = u.v;
    }

    f32x16 acc, zacc;
#pragma unroll
    for (int r = 0; r < 16; ++r) { acc[r] = 3.0e38f; zacc[r] = 0.f; }

    asm volatile("s_waitcnt vmcnt(0)" ::: "memory");
    __syncthreads();   // whole chunk resident; only barrier in the kernel

    // per-lane read slot (sigma-permuted at prep time): loop-invariant
    const char* rb = (const char*)tile + sigma(col * 2 + ksel) * 16;

    // ---- 1-deep pipelined loop: 16 iters x 2048 B = 32 KB exactly ----
    U8 u0, u1;
    u0.u = *(const uint4*)(rb);
    u1.u = *(const uint4*)(rb + 1024);
    rb += 2048;
    f32x16 d0 = __builtin_amdgcn_mfma_f32_32x32x16_f16(a0, u0.v, zacc, 0, 0, 0);
    f32x16 d1 = __builtin_amdgcn_mfma_f32_32x32x16_f16(a0, u1.v, zacc, 0, 0, 0);

#pragma unroll 1
    for (int it = 1; it < 16; ++it) {
        U8 v0, v1;                           // issue next B loads (no wait yet)
        v0.u = *(const uint4*)(rb);
        v1.u = *(const uint4*)(rb + 1024);
        rb += 2048;
        // fold PREVIOUS iteration's MFMA results
#pragma unroll
        for (int r = 0; r < 16; ++r)   // v_min3_f32
            acc[r] = fminf(fminf(d0[r], d1[r]), acc[r]);
        d0 = __builtin_amdgcn_mfma_f32_32x32x16_f16(a0, v0.v, zacc, 0, 0, 0);
        d1 = __builtin_amdgcn_mfma_f32_32x32x16_f16(a0, v1.v, zacc, 0, 0, 0);
    }
#pragma unroll
    for (int r = 0; r < 16; ++r)
        acc[r] = fminf(fminf(d0[r], d1[r]), acc[r]);

    // ---- min over the 32 db-columns; store per-chunk partials ----
#pragma unroll
    for (int r = 0; r < 16; ++r) {
        float v = acc[r];
#pragma unroll
        for (int off = 1; off < 32; off <<= 1)
            v = fminf(v, __shfl_xor(v, off, 64));
        if (col == 0) {
            // C/D layout (HW-verified): col=lane&31, row=(r&3)+8*(r>>2)+4*ksel
            int row = (r & 3) + 8 * (r >> 2) + 4 * ksel;
            int q0  = qw + row;
            part[((size_t)blockIdx.z * NQ + q0) * DC + blockIdx.y] = v;
        }
    }
}

// 16-way min over chunks, add |q|^2 (recomputed from raw input), clamp, average.
__global__ __launch_bounds__(BLOCK) void chamfer_reduce(
    const float* __restrict__ part, const float* __restrict__ Xc,
    const float* __restrict__ Xt, float* __restrict__ out)
{
    __shared__ float red[4];
    int e = blockIdx.x * BLOCK + threadIdx.x;   // 0 .. 2*NQ-1

    const float4* pb = (const float4*)(part + (size_t)e * DC);
    float mn = 3.4e38f;
#pragma unroll
    for (int j = 0; j < DC / 4; ++j) {
        float4 m = pb[j];
        mn = fminf(mn, fminf(fminf(m.x, m.y), fminf(m.z, m.w)));
    }

    const float* X = (e < NQ) ? Xc : Xt;
    int q = (e < NQ) ? e : e - NQ;
    float x = X[3 * q], y = X[3 * q + 1], z = X[3 * q + 2];
    float n2 = fmaf(x, x, fmaf(y, y, z * z));
    float s = fmaxf(mn + n2, 0.0f) * (1.0f / 16384.0f);

#pragma unroll
    for (int off = 32; off > 0; off >>= 1) s += __shfl_down(s, off, 64);
    int wv = threadIdx.x >> 6, ln = threadIdx.x & 63;
    if (ln == 0) red[wv] = s;
    __syncthreads();
    if (threadIdx.x == 0) atomicAdd(out, red[0] + red[1] + red[2] + red[3]);
}

extern "C" void kernel_launch(void* const* d_in, const int* in_sizes, int n_in,
                              void* d_out, int out_size, void* d_ws, size_t ws_size,
                              hipStream_t stream) {
    const float* Xc = (const float*)d_in[0];
    const float* Xt = (const float*)d_in[1];
    float* out = (float*)d_out;

    // ws: Ac | At | Bc | Bt (512 KB each) | part (2*16384*16 f32 = 2 MB)
    uint4* Ac = (uint4*)d_ws;
    uint4* At = Ac + 2 * NQ;
    uint4* Bc = At + 2 * NQ;
    uint4* Bt = Bc + 2 * NQ;
    float* part = (float*)(Bt + 2 * NQ);

    chamfer_prep<<<NQ / BLOCK, BLOCK, 0, stream>>>(Xc, Xt, Ac, At, Bc, Bt, out);

    dim3 grid(NQ / 128 /*128*/, DC, 2);   // 4096 blocks, 4 waves, 1 A-tile/wave
    chamfer_pass<<<grid, BLOCK, 0, stream>>>(Ac, At, Bc, Bt, part);

    chamfer_reduce<<<(2 * NQ) / BLOCK, BLOCK, 0, stream>>>(part, Xc, Xt, out);
}